// Round 1
// baseline (1004.161 us; speedup 1.0000x reference)
//
#include <hip/hip_runtime.h>
#include <hip/hip_bf16.h>
#include <float.h>

#define LC 1024
#define CS 768
#define NH 16
#define DH 48
#define CP 128

typedef __attribute__((ext_vector_type(8))) short short8;
typedef __attribute__((ext_vector_type(4))) float f32x4;
typedef __attribute__((ext_vector_type(4))) unsigned short ushort4v;

// RNE f32 -> bf16 (finite inputs only)
__device__ inline unsigned short f2b(float f){
    unsigned u = __builtin_bit_cast(unsigned, f);
    unsigned r = 0x7FFFu + ((u >> 16) & 1u);
    return (unsigned short)((u + r) >> 16);
}

// ---------------- K0a: convert s (f32 -> bf16) ----------------
__global__ void k_convert(const float* __restrict__ src, unsigned short* __restrict__ dst, int n){
    int i = (blockIdx.x * blockDim.x + threadIdx.x) * 4;
    if (i < n){
        float4 v = *reinterpret_cast<const float4*>(src + i);
        ushort4v o;
        o[0] = f2b(v.x); o[1] = f2b(v.y); o[2] = f2b(v.z); o[3] = f2b(v.w);
        *reinterpret_cast<ushort4v*>(dst + i) = o;
    }
}

// ---------------- K0b: transpose+convert 5 weight matrices ----------------
struct P5 { const float* s[5]; unsigned short* d[5]; };

__global__ void k_transpose_w5(P5 p){
    __shared__ float t[32][33];
    int m = blockIdx.z;
    const float* W = p.s[m];
    unsigned short* O = p.d[m];
    int i0 = blockIdx.x * 32, o0 = blockIdx.y * 32;
    int tx = threadIdx.x & 31, ty = threadIdx.x >> 5;  // ty 0..7
    for (int r = 0; r < 32; r += 8)
        t[ty + r][tx] = W[(long)(i0 + ty + r) * CS + o0 + tx];
    __syncthreads();
    for (int r = 0; r < 32; r += 8)
        O[(long)(o0 + ty + r) * CS + i0 + tx] = f2b(t[tx][ty + r]);
}

// ---------------- K1.5: transpose v (bf16 [1024][768] -> [768][1024]) ----------------
__global__ void k_transpose_v(const unsigned short* __restrict__ v, unsigned short* __restrict__ vt){
    __shared__ unsigned short t[32][33];
    int j0 = blockIdx.x * 32, c0 = blockIdx.y * 32;
    int tx = threadIdx.x & 31, ty = threadIdx.x >> 5;
    for (int r = 0; r < 32; r += 8)
        t[ty + r][tx] = v[(long)(j0 + ty + r) * CS + c0 + tx];
    __syncthreads();
    for (int r = 0; r < 32; r += 8)
        vt[(long)(c0 + ty + r) * LC + j0 + tx] = t[tx][ty + r];
}

// ---------------- GEMM: C[1024,768] = A[1024,768]@B^T + bias ----------------
// mode 0/1/2: bf16 out (q/k/v). mode 3: sigmoid -> f32 out (gate). mode 4: gate*(acc+bias) -> f32 out (y).
__global__ __launch_bounds__(256) void k_gemm(
    const unsigned short* __restrict__ A,     // [1024][768] bf16
    const unsigned short* __restrict__ B,     // [768 out][768 in] bf16 (pre-transposed W)
    const float* __restrict__ bias,           // [768]
    void* __restrict__ out,
    const float* __restrict__ gate,
    int mode)
{
    __shared__ unsigned short As[64][40];     // +8 pad: row stride 80B -> conflict-free frags
    __shared__ unsigned short Bs[64][40];
    int m0 = blockIdx.x * 64, n0 = blockIdx.y * 64;
    int t = threadIdx.x, lane = t & 63, w = t >> 6;
    int l15 = lane & 15, l4 = lane >> 4;
    f32x4 zero4 = {0.f, 0.f, 0.f, 0.f};
    f32x4 acc[4] = {zero4, zero4, zero4, zero4};

    for (int kk = 0; kk < CS; kk += 32){
        int row = t >> 2, c = (t & 3) * 8;
        *reinterpret_cast<short8*>(&As[row][c]) =
            *reinterpret_cast<const short8*>(&A[(long)(m0 + row) * CS + kk + c]);
        *reinterpret_cast<short8*>(&Bs[row][c]) =
            *reinterpret_cast<const short8*>(&B[(long)(n0 + row) * CS + kk + c]);
        __syncthreads();
        short8 af = *reinterpret_cast<const short8*>(&As[w * 16 + l15][l4 * 8]);
        for (int nt = 0; nt < 4; nt++){
            short8 bf = *reinterpret_cast<const short8*>(&Bs[nt * 16 + l15][l4 * 8]);
            acc[nt] = __builtin_amdgcn_mfma_f32_16x16x32_bf16(af, bf, acc[nt], 0, 0, 0);
        }
        __syncthreads();
    }
    for (int nt = 0; nt < 4; nt++){
        int col = n0 + nt * 16 + l15;
        float bv = bias[col];
        for (int r = 0; r < 4; r++){
            int rowi = m0 + w * 16 + l4 * 4 + r;
            float v = acc[nt][r] + bv;
            if (mode <= 2){
                ((unsigned short*)out)[(long)rowi * CS + col] = f2b(v);
            } else if (mode == 3){
                ((float*)out)[(long)rowi * CS + col] = 1.0f / (1.0f + expf(-v));
            } else {
                ((float*)out)[(long)rowi * CS + col] = gate[(long)rowi * CS + col] * v;
            }
        }
    }
}

// ---------------- K2: fused logits (z*Wz MFMA + QK^T MFMA + biases + mask) ----------------
// grid (64 i-blocks, 8 j-chunks), 512 threads. Writes raw logits into attn buffer,
// online-softmax partials (m,s) per row-chunk into stats.
__global__ __launch_bounds__(512) void k_logits(
    const float* __restrict__ z,
    const float* __restrict__ Wz,
    const unsigned short* __restrict__ qb,
    const unsigned short* __restrict__ kb,
    const float* __restrict__ dist,
    const float* __restrict__ prior,
    const int* __restrict__ mask,
    float* __restrict__ attn,
    float* __restrict__ stats)
{
    __shared__ float Ls[16][16][17];       // [i][j][h] pad 17
    __shared__ float dist_s[16][16][17];
    __shared__ float prior_s[16][16];
    __shared__ int   mask_s[16][16];

    int I0 = blockIdx.x * 16;
    int chunk = blockIdx.y;
    int t = threadIdx.x, lane = t & 63, w = t >> 6;
    int l15 = lane & 15, l4 = lane >> 4;
    const float scale = 0.14433756729740643f;   // 1/sqrt(48)

    // Wz B-fragments: B[k=c][n=h], Wz stored [128][16] f32
    short8 wzf[4];
    for (int ck = 0; ck < 4; ck++){
        short8 f;
        for (int b = 0; b < 8; b++){
            int c = ck * 32 + l4 * 8 + b;
            f[b] = (short)f2b(Wz[c * 16 + l15]);
        }
        wzf[ck] = f;
    }
    // q A-fragments hoisted (rows I0..I0+15 fixed per block); 2 heads per wave
    short8 qf0[2], qf1[2];
    for (int rep = 0; rep < 2; rep++){
        int h = w * 2 + rep;
        const unsigned short* qrow = qb + (long)(I0 + l15) * CS + h * 48;
        qf0[rep] = *reinterpret_cast<const short8*>(qrow + l4 * 8);
        short8 zz; for (int b = 0; b < 8; b++) zz[b] = 0;
        qf1[rep] = zz;
        if (l4 < 2) qf1[rep] = *reinterpret_cast<const short8*>(qrow + 32 + l4 * 8);
    }

    float mreg[8], sreg[8];
    for (int p = 0; p < 8; p++){ mreg[p] = -FLT_MAX; sreg[p] = 0.f; }

    for (int jt = 0; jt < 8; jt++){
        int j0 = chunk * 128 + jt * 16;

        // Phase A: z-bias MFMA -> Ls  (+ stage dist/prior/mask)
        for (int rep = 0; rep < 2; rep++){
            int i = w * 2 + rep;
            f32x4 acc = {0.f, 0.f, 0.f, 0.f};
            const float* zrow = z + ((long)(I0 + i) * LC + (j0 + l15)) * CP;
            for (int ck = 0; ck < 4; ck++){
                float4 z0 = *reinterpret_cast<const float4*>(zrow + ck * 32 + l4 * 8);
                float4 z1 = *reinterpret_cast<const float4*>(zrow + ck * 32 + l4 * 8 + 4);
                short8 zf;
                zf[0] = f2b(z0.x); zf[1] = f2b(z0.y); zf[2] = f2b(z0.z); zf[3] = f2b(z0.w);
                zf[4] = f2b(z1.x); zf[5] = f2b(z1.y); zf[6] = f2b(z1.z); zf[7] = f2b(z1.w);
                acc = __builtin_amdgcn_mfma_f32_16x16x32_bf16(zf, wzf[ck], acc, 0, 0, 0);
            }
            for (int r = 0; r < 4; r++) Ls[i][l4 * 4 + r][l15] = acc[r];  // D: row=j', col=h
        }
        {   // stage dist tile (16i x 16j x 16h): coalesced read, padded LDS write
            int s = t * 8;
            int di = s >> 8, rem = s & 255;
            const float* src = dist + (((long)(I0 + di) * LC + j0) * NH) + rem;
            float4 d0 = *reinterpret_cast<const float4*>(src);
            float4 d1 = *reinterpret_cast<const float4*>(src + 4);
            float dv[8] = {d0.x, d0.y, d0.z, d0.w, d1.x, d1.y, d1.z, d1.w};
            for (int b = 0; b < 8; b++){
                int jj = (rem + b) >> 4, hh = (rem + b) & 15;
                dist_s[di][jj][hh] = dv[b];
            }
            if (t < 256){
                int ii = t >> 4, jj = t & 15;
                prior_s[ii][jj] = prior[(long)(I0 + ii) * LC + j0 + jj];
                mask_s[ii][jj]  = mask [(long)(I0 + ii) * LC + j0 + jj];
            }
        }
        __syncthreads();

        // Phase B: QK^T MFMA, scaled RMW into Ls
        for (int rep = 0; rep < 2; rep++){
            int h = w * 2 + rep;
            const unsigned short* krow = kb + (long)(j0 + l15) * CS + h * 48;
            short8 kf0 = *reinterpret_cast<const short8*>(krow + l4 * 8);
            short8 kf1; for (int b = 0; b < 8; b++) kf1[b] = 0;
            if (l4 < 2) kf1 = *reinterpret_cast<const short8*>(krow + 32 + l4 * 8);
            f32x4 acc = {0.f, 0.f, 0.f, 0.f};
            acc = __builtin_amdgcn_mfma_f32_16x16x32_bf16(qf0[rep], kf0, acc, 0, 0, 0);
            acc = __builtin_amdgcn_mfma_f32_16x16x32_bf16(qf1[rep], kf1, acc, 0, 0, 0);
            for (int r = 0; r < 4; r++)
                Ls[l4 * 4 + r][l15][h] += acc[r] * scale;   // D: row=i', col=j'
        }
        __syncthreads();

        // Phase C: combine, write raw logits, online softmax partials
        int qw = t >> 4, jl = t & 15;
        for (int p = 0; p < 8; p++){
            int task = p * 32 + qw;
            int ti = task >> 4, th = task & 15;
            float lg = Ls[ti][jl][th] + dist_s[ti][jl][th] + prior_s[ti][jl];
            bool mk = (mask_s[ti][jl] != 0);
            lg = mk ? lg : -FLT_MAX;
            attn[(long)th * LC * LC + (long)(I0 + ti) * LC + j0 + jl] = lg;
            float mt = lg;
            for (int mo = 1; mo < 16; mo <<= 1) mt = fmaxf(mt, __shfl_xor(mt, mo));
            float e = mk ? expf(lg - mt) : 0.f;
            float st = e;
            for (int mo = 1; mo < 16; mo <<= 1) st += __shfl_xor(st, mo);
            if (mt > mreg[p]){
                sreg[p] = sreg[p] * expf(mreg[p] - mt) + st;
                mreg[p] = mt;
            } else {
                sreg[p] += st * expf(mt - mreg[p]);
            }
        }
        __syncthreads();
    }
    if ((t & 15) == 0){
        int qw = t >> 4;
        for (int p = 0; p < 8; p++){
            int task = p * 32 + qw;
            int ti = task >> 4, th = task & 15;
            long off = (((long)th * LC + (I0 + ti)) * 8 + chunk) * 2;
            stats[off]     = mreg[p];
            stats[off + 1] = sreg[p];
        }
    }
}

// ---------------- K3: finalize softmax in-place + ctx = attn @ v ----------------
__global__ __launch_bounds__(256) void k_ctx(
    float* __restrict__ attn,
    const unsigned short* __restrict__ vt,    // [768][1024] bf16
    const float* __restrict__ stats,
    unsigned short* __restrict__ ctx)         // [1024][768] bf16
{
    int h = blockIdx.x, ib = blockIdx.y;
    int t = threadIdx.x, lane = t & 63, w = t >> 6;
    int l15 = lane & 15, l4 = lane >> 4;
    int i = ib * 64 + w * 16 + l15;

    const float* sp = stats + ((long)h * LC + i) * 16;   // 8 chunks x 2
    float M = -FLT_MAX;
    for (int c = 0; c < 8; c++) M = fmaxf(M, sp[c * 2]);
    float S = 0.f;
    for (int c = 0; c < 8; c++) S += sp[c * 2 + 1] * expf(sp[c * 2] - M);
    float invS = 1.0f / S;

    f32x4 zero4 = {0.f, 0.f, 0.f, 0.f};
    f32x4 acc[3] = {zero4, zero4, zero4};
    float* arow = attn + (long)h * LC * LC + (long)i * LC;

    for (int jk = 0; jk < LC; jk += 32){
        float4 a0 = *reinterpret_cast<const float4*>(arow + jk + l4 * 8);
        float4 a1 = *reinterpret_cast<const float4*>(arow + jk + l4 * 8 + 4);
        float p[8] = {a0.x, a0.y, a0.z, a0.w, a1.x, a1.y, a1.z, a1.w};
        short8 pf;
        for (int b = 0; b < 8; b++){
            float e = expf(p[b] - M) * invS;   // masked (-FLT_MAX) -> 0
            p[b] = e;
            pf[b] = (short)f2b(e);
        }
        float4 o0 = {p[0], p[1], p[2], p[3]}, o1 = {p[4], p[5], p[6], p[7]};
        *reinterpret_cast<float4*>(arow + jk + l4 * 8) = o0;
        *reinterpret_cast<float4*>(arow + jk + l4 * 8 + 4) = o1;
        for (int dt = 0; dt < 3; dt++){
            const unsigned short* vrow = vt + (long)(h * 48 + dt * 16 + l15) * LC + jk + l4 * 8;
            short8 bf = *reinterpret_cast<const short8*>(vrow);
            acc[dt] = __builtin_amdgcn_mfma_f32_16x16x32_bf16(pf, bf, acc[dt], 0, 0, 0);
        }
    }
    for (int dt = 0; dt < 3; dt++)
        for (int r = 0; r < 4; r++){
            int rowi = ib * 64 + w * 16 + l4 * 4 + r;
            ctx[(long)rowi * CS + h * 48 + dt * 16 + l15] = f2b(acc[dt][r]);
        }
}

// ---------------- launch ----------------
extern "C" void kernel_launch(void* const* d_in, const int* in_sizes, int n_in,
                              void* d_out, int out_size, void* d_ws, size_t ws_size,
                              hipStream_t stream)
{
    const float* s     = (const float*)d_in[0];
    const float* z     = (const float*)d_in[1];
    const int*   mask  = (const int*)  d_in[2];
    const float* dist  = (const float*)d_in[3];
    const float* prior = (const float*)d_in[4];
    const float* Wq = (const float*)d_in[5];  const float* bq = (const float*)d_in[6];
    const float* Wk = (const float*)d_in[7];  const float* bk = (const float*)d_in[8];
    const float* Wv = (const float*)d_in[9];  const float* bv = (const float*)d_in[10];
    const float* Wz = (const float*)d_in[11];
    const float* Wo = (const float*)d_in[12]; const float* bo = (const float*)d_in[13];
    const float* Wg = (const float*)d_in[14]; const float* bg = (const float*)d_in[15];

    char* ws = (char*)d_ws;
    const size_t SZ_BF = (size_t)LC * CS * 2;       // 1.5 MB
    const size_t SZ_WT = (size_t)CS * CS * 2;       // 1.125 MB
    unsigned short* sb   = (unsigned short*)(ws);
    unsigned short* wqt  = (unsigned short*)(ws + SZ_BF);
    unsigned short* wkt  = (unsigned short*)(ws + SZ_BF + SZ_WT);
    unsigned short* wvt  = (unsigned short*)(ws + SZ_BF + 2 * SZ_WT);
    unsigned short* wgt  = (unsigned short*)(ws + SZ_BF + 3 * SZ_WT);
    unsigned short* wot  = (unsigned short*)(ws + SZ_BF + 4 * SZ_WT);
    unsigned short* qb   = (unsigned short*)(ws + SZ_BF + 5 * SZ_WT);
    unsigned short* kb   = (unsigned short*)(ws + 2 * SZ_BF + 5 * SZ_WT);
    unsigned short* vb   = (unsigned short*)(ws + 3 * SZ_BF + 5 * SZ_WT);
    unsigned short* vt   = (unsigned short*)(ws + 4 * SZ_BF + 5 * SZ_WT);
    float*          gate = (float*)        (ws + 5 * SZ_BF + 5 * SZ_WT);
    unsigned short* ctxb = (unsigned short*)(ws + 5 * SZ_BF + 5 * SZ_WT + (size_t)LC * CS * 4);
    float*          stats= (float*)        (ws + 6 * SZ_BF + 5 * SZ_WT + (size_t)LC * CS * 4);
    // total ~19.6 MB of workspace

    float* y    = (float*)d_out;
    float* attn = (float*)d_out + (size_t)LC * CS;

    k_convert<<<768, 256, 0, stream>>>(s, sb, LC * CS);
    P5 p;
    p.s[0] = Wq; p.s[1] = Wk; p.s[2] = Wv; p.s[3] = Wg; p.s[4] = Wo;
    p.d[0] = wqt; p.d[1] = wkt; p.d[2] = wvt; p.d[3] = wgt; p.d[4] = wot;
    k_transpose_w5<<<dim3(24, 24, 5), 256, 0, stream>>>(p);

    k_gemm<<<dim3(16, 12), 256, 0, stream>>>(sb, wqt, bq, qb, nullptr, 0);
    k_gemm<<<dim3(16, 12), 256, 0, stream>>>(sb, wkt, bk, kb, nullptr, 1);
    k_gemm<<<dim3(16, 12), 256, 0, stream>>>(sb, wvt, bv, vb, nullptr, 2);
    k_gemm<<<dim3(16, 12), 256, 0, stream>>>(sb, wgt, bg, gate, nullptr, 3);
    k_transpose_v<<<dim3(32, 24), 256, 0, stream>>>(vb, vt);

    k_logits<<<dim3(64, 8), 512, 0, stream>>>(z, Wz, qb, kb, dist, prior, mask, attn, stats);
    k_ctx<<<dim3(16, 16), 256, 0, stream>>>(attn, vt, stats, ctxb);
    k_gemm<<<dim3(16, 12), 256, 0, stream>>>(ctxb, wot, bo, y, gate, 4);
}

// Round 2
// 967.135 us; speedup vs baseline: 1.0383x; 1.0383x over previous
//
#include <hip/hip_runtime.h>
#include <hip/hip_bf16.h>
#include <float.h>

#define LC 1024
#define CS 768
#define NH 16
#define DH 48
#define CP 128

typedef __attribute__((ext_vector_type(8))) short short8;
typedef __attribute__((ext_vector_type(4))) float f32x4;
typedef __attribute__((ext_vector_type(4))) unsigned short ushort4v;

// RNE f32 -> bf16 (finite inputs only)
__device__ inline unsigned short f2b(float f){
    unsigned u = __builtin_bit_cast(unsigned, f);
    unsigned r = 0x7FFFu + ((u >> 16) & 1u);
    return (unsigned short)((u + r) >> 16);
}

// ---------------- K0a: convert s (f32 -> bf16) ----------------
__global__ void k_convert(const float* __restrict__ src, unsigned short* __restrict__ dst, int n){
    int i = (blockIdx.x * blockDim.x + threadIdx.x) * 4;
    if (i < n){
        float4 v = *reinterpret_cast<const float4*>(src + i);
        ushort4v o;
        o[0] = f2b(v.x); o[1] = f2b(v.y); o[2] = f2b(v.z); o[3] = f2b(v.w);
        *reinterpret_cast<ushort4v*>(dst + i) = o;
    }
}

// ---------------- K0b: transpose+convert 5 weight matrices ----------------
struct P5 { const float* s[5]; unsigned short* d[5]; };

__global__ void k_transpose_w5(P5 p){
    __shared__ float t[32][33];
    int m = blockIdx.z;
    const float* W = p.s[m];
    unsigned short* O = p.d[m];
    int i0 = blockIdx.x * 32, o0 = blockIdx.y * 32;
    int tx = threadIdx.x & 31, ty = threadIdx.x >> 5;  // ty 0..7
    for (int r = 0; r < 32; r += 8)
        t[ty + r][tx] = W[(long)(i0 + ty + r) * CS + o0 + tx];
    __syncthreads();
    for (int r = 0; r < 32; r += 8)
        O[(long)(o0 + ty + r) * CS + i0 + tx] = f2b(t[tx][ty + r]);
}

// ---------------- transpose v (bf16 [1024][768] -> [768][1024]) ----------------
__global__ void k_transpose_v(const unsigned short* __restrict__ v, unsigned short* __restrict__ vt){
    __shared__ unsigned short t[32][33];
    int j0 = blockIdx.x * 32, c0 = blockIdx.y * 32;
    int tx = threadIdx.x & 31, ty = threadIdx.x >> 5;
    for (int r = 0; r < 32; r += 8)
        t[ty + r][tx] = v[(long)(j0 + ty + r) * CS + c0 + tx];
    __syncthreads();
    for (int r = 0; r < 32; r += 8)
        vt[(long)(c0 + ty + r) * LC + j0 + tx] = t[tx][ty + r];
}

// ---------------- merged QKVG GEMM: [1024,768] @ [768,3072(out)] ----------------
// B = wcat [3072 out][768 in] bf16 (q|k|v|g stacked). seg = blockIdx.y/12.
__global__ __launch_bounds__(256) void k_gemm_qkvg(
    const unsigned short* __restrict__ A,
    const unsigned short* __restrict__ B,
    const float* __restrict__ bq, const float* __restrict__ bk,
    const float* __restrict__ bv, const float* __restrict__ bg,
    unsigned short* __restrict__ oq, unsigned short* __restrict__ ok,
    unsigned short* __restrict__ ov, float* __restrict__ og)
{
    __shared__ unsigned short As[64][40];
    __shared__ unsigned short Bs[64][40];
    int m0 = blockIdx.x * 64, n0 = blockIdx.y * 64;
    int seg = blockIdx.y / 12;            // 12 y-blocks of 64 per 768-col segment
    int ncol0 = n0 - seg * CS;
    int t = threadIdx.x, lane = t & 63, w = t >> 6;
    int l15 = lane & 15, l4 = lane >> 4;
    f32x4 zero4 = {0.f, 0.f, 0.f, 0.f};
    f32x4 acc[4] = {zero4, zero4, zero4, zero4};

    for (int kk = 0; kk < CS; kk += 32){
        int row = t >> 2, c = (t & 3) * 8;
        *reinterpret_cast<short8*>(&As[row][c]) =
            *reinterpret_cast<const short8*>(&A[(long)(m0 + row) * CS + kk + c]);
        *reinterpret_cast<short8*>(&Bs[row][c]) =
            *reinterpret_cast<const short8*>(&B[(long)(n0 + row) * CS + kk + c]);
        __syncthreads();
        short8 af = *reinterpret_cast<const short8*>(&As[w * 16 + l15][l4 * 8]);
        for (int nt = 0; nt < 4; nt++){
            short8 bf = *reinterpret_cast<const short8*>(&Bs[nt * 16 + l15][l4 * 8]);
            acc[nt] = __builtin_amdgcn_mfma_f32_16x16x32_bf16(af, bf, acc[nt], 0, 0, 0);
        }
        __syncthreads();
    }
    const float* bias = (seg == 0) ? bq : (seg == 1) ? bk : (seg == 2) ? bv : bg;
    unsigned short* obf = (seg == 0) ? oq : (seg == 1) ? ok : ov;
    for (int nt = 0; nt < 4; nt++){
        int col = ncol0 + nt * 16 + l15;
        float bvv = bias[col];
        for (int r = 0; r < 4; r++){
            int rowi = m0 + w * 16 + l4 * 4 + r;
            float v = acc[nt][r] + bvv;
            if (seg < 3){
                obf[(long)rowi * CS + col] = f2b(v);
            } else {
                og[(long)rowi * CS + col] = 1.0f / (1.0f + __expf(-v));
            }
        }
    }
}

// ---------------- final GEMM: y = gate * (ctx @ Wo^T + bo) ----------------
__global__ __launch_bounds__(256) void k_gemm_out(
    const unsigned short* __restrict__ A,
    const unsigned short* __restrict__ B,
    const float* __restrict__ bias,
    const float* __restrict__ gate,
    float* __restrict__ out)
{
    __shared__ unsigned short As[64][40];
    __shared__ unsigned short Bs[64][40];
    int m0 = blockIdx.x * 64, n0 = blockIdx.y * 64;
    int t = threadIdx.x, lane = t & 63, w = t >> 6;
    int l15 = lane & 15, l4 = lane >> 4;
    f32x4 zero4 = {0.f, 0.f, 0.f, 0.f};
    f32x4 acc[4] = {zero4, zero4, zero4, zero4};

    for (int kk = 0; kk < CS; kk += 32){
        int row = t >> 2, c = (t & 3) * 8;
        *reinterpret_cast<short8*>(&As[row][c]) =
            *reinterpret_cast<const short8*>(&A[(long)(m0 + row) * CS + kk + c]);
        *reinterpret_cast<short8*>(&Bs[row][c]) =
            *reinterpret_cast<const short8*>(&B[(long)(n0 + row) * CS + kk + c]);
        __syncthreads();
        short8 af = *reinterpret_cast<const short8*>(&As[w * 16 + l15][l4 * 8]);
        for (int nt = 0; nt < 4; nt++){
            short8 bf = *reinterpret_cast<const short8*>(&Bs[nt * 16 + l15][l4 * 8]);
            acc[nt] = __builtin_amdgcn_mfma_f32_16x16x32_bf16(af, bf, acc[nt], 0, 0, 0);
        }
        __syncthreads();
    }
    for (int nt = 0; nt < 4; nt++){
        int col = n0 + nt * 16 + l15;
        float bvv = bias[col];
        for (int r = 0; r < 4; r++){
            int rowi = m0 + w * 16 + l4 * 4 + r;
            out[(long)rowi * CS + col] = gate[(long)rowi * CS + col] * (acc[nt][r] + bvv);
        }
    }
}

// ---------------- K2: fused logits (z*Wz + QK^T + biases + mask + stats) ----------------
// grid (64, 8), 512 thr. 2 barriers per 16-j tile; z/dist/prior/mask prefetched a tile ahead.
__global__ __launch_bounds__(512, 4) void k_logits(
    const float* __restrict__ z,
    const float* __restrict__ Wz,
    const unsigned short* __restrict__ qb,
    const unsigned short* __restrict__ kb,
    const float* __restrict__ dist,
    const float* __restrict__ prior,
    const int* __restrict__ mask,
    float* __restrict__ attn,
    float* __restrict__ stats)
{
    __shared__ float Ls [16][16][17];      // z-bias: [i][j][h]
    __shared__ float Ls2[16][16][17];      // qk:     [i][j][h]
    __shared__ float dist_s[16][16][17];
    __shared__ float prior_s[16][16];
    __shared__ int   mask_s[16][16];

    int I0 = blockIdx.x * 16;
    int chunk = blockIdx.y;
    int t = threadIdx.x, lane = t & 63, w = t >> 6;
    int l15 = lane & 15, l4 = lane >> 4;
    const float scale = 0.14433756729740643f;   // 1/sqrt(48)

    // Wz B-fragments: B[k=c][n=h]
    short8 wzf[4];
    for (int ck = 0; ck < 4; ck++){
        short8 f;
        for (int b = 0; b < 8; b++){
            int c = ck * 32 + l4 * 8 + b;
            f[b] = (short)f2b(Wz[c * 16 + l15]);
        }
        wzf[ck] = f;
    }
    // q A-fragments hoisted; 2 heads per wave
    short8 qf0[2], qf1[2];
    for (int rep = 0; rep < 2; rep++){
        int h = w * 2 + rep;
        const unsigned short* qrow = qb + (long)(I0 + l15) * CS + h * 48;
        qf0[rep] = *reinterpret_cast<const short8*>(qrow + l4 * 8);
        short8 zz; for (int b = 0; b < 8; b++) zz[b] = 0;
        qf1[rep] = zz;
        if (l4 < 2) qf1[rep] = *reinterpret_cast<const short8*>(qrow + 32 + l4 * 8);
    }

    float mreg[8], sreg[8];
    for (int p = 0; p < 8; p++){ mreg[p] = -FLT_MAX; sreg[p] = 0.f; }

    // prefetch state
    float4 pf[8];                 // rep0 z tile (next)
    float4 dd0, dd1;              // dist (next)
    float pp = 0.f; int mm = 0;   // prior/mask (next)
    int sofs = t * 8, di = sofs >> 8, rem = sofs & 255;
    int pr_i = t >> 4, pr_j = t & 15;   // valid when t < 256

    int row0 = I0 + w * 2;

    for (int jt = 0; jt < 8; jt++){
        int j0 = chunk * 128 + jt * 16;

        if (jt == 0){
            const float* zr = z + ((long)row0 * LC + (j0 + l15)) * CP + l4 * 8;
            pf[0] = *(const float4*)(zr);      pf[1] = *(const float4*)(zr + 4);
            pf[2] = *(const float4*)(zr + 32); pf[3] = *(const float4*)(zr + 36);
            pf[4] = *(const float4*)(zr + 64); pf[5] = *(const float4*)(zr + 68);
            pf[6] = *(const float4*)(zr + 96); pf[7] = *(const float4*)(zr + 100);
            const float* dsrc = dist + (((long)(I0 + di) * LC + j0) * NH) + rem;
            dd0 = *(const float4*)dsrc; dd1 = *(const float4*)(dsrc + 4);
            if (t < 256){
                pp = prior[(long)(I0 + pr_i) * LC + j0 + pr_j];
                mm = mask [(long)(I0 + pr_i) * LC + j0 + pr_j];
            }
        }

        // ---- write staged aux into LDS ----
        {
            float dv[8] = {dd0.x, dd0.y, dd0.z, dd0.w, dd1.x, dd1.y, dd1.z, dd1.w};
            #pragma unroll
            for (int b = 0; b < 8; b++){
                int jj = (rem + b) >> 4, hh = (rem + b) & 15;
                dist_s[di][jj][hh] = dv[b];
            }
            if (t < 256){ prior_s[pr_i][pr_j] = pp; mask_s[pr_i][pr_j] = mm; }
        }

        // ---- z MFMA rep0 (from prefetched regs) ----
        {
            f32x4 acc = {0.f, 0.f, 0.f, 0.f};
            #pragma unroll
            for (int ck = 0; ck < 4; ck++){
                float4 z0 = pf[ck * 2], z1 = pf[ck * 2 + 1];
                short8 zf;
                zf[0] = f2b(z0.x); zf[1] = f2b(z0.y); zf[2] = f2b(z0.z); zf[3] = f2b(z0.w);
                zf[4] = f2b(z1.x); zf[5] = f2b(z1.y); zf[6] = f2b(z1.z); zf[7] = f2b(z1.w);
                acc = __builtin_amdgcn_mfma_f32_16x16x32_bf16(zf, wzf[ck], acc, 0, 0, 0);
            }
            #pragma unroll
            for (int r = 0; r < 4; r++) Ls[w * 2][l4 * 4 + r][l15] = acc[r];
        }
        // ---- z MFMA rep1 (direct) ----
        {
            const float* zr = z + ((long)(row0 + 1) * LC + (j0 + l15)) * CP + l4 * 8;
            f32x4 acc = {0.f, 0.f, 0.f, 0.f};
            #pragma unroll
            for (int ck = 0; ck < 4; ck++){
                float4 z0 = *(const float4*)(zr + ck * 32);
                float4 z1 = *(const float4*)(zr + ck * 32 + 4);
                short8 zf;
                zf[0] = f2b(z0.x); zf[1] = f2b(z0.y); zf[2] = f2b(z0.z); zf[3] = f2b(z0.w);
                zf[4] = f2b(z1.x); zf[5] = f2b(z1.y); zf[6] = f2b(z1.z); zf[7] = f2b(z1.w);
                acc = __builtin_amdgcn_mfma_f32_16x16x32_bf16(zf, wzf[ck], acc, 0, 0, 0);
            }
            #pragma unroll
            for (int r = 0; r < 4; r++) Ls[w * 2 + 1][l4 * 4 + r][l15] = acc[r];
        }

        // ---- prefetch next tile (z rep0 + aux) ----
        if (jt < 7){
            int j0n = j0 + 16;
            const float* zr = z + ((long)row0 * LC + (j0n + l15)) * CP + l4 * 8;
            pf[0] = *(const float4*)(zr);      pf[1] = *(const float4*)(zr + 4);
            pf[2] = *(const float4*)(zr + 32); pf[3] = *(const float4*)(zr + 36);
            pf[4] = *(const float4*)(zr + 64); pf[5] = *(const float4*)(zr + 68);
            pf[6] = *(const float4*)(zr + 96); pf[7] = *(const float4*)(zr + 100);
            const float* dsrc = dist + (((long)(I0 + di) * LC + j0n) * NH) + rem;
            dd0 = *(const float4*)dsrc; dd1 = *(const float4*)(dsrc + 4);
            if (t < 256){
                pp = prior[(long)(I0 + pr_i) * LC + j0n + pr_j];
                mm = mask [(long)(I0 + pr_i) * LC + j0n + pr_j];
            }
        }

        // ---- QK^T MFMA into Ls2 ----
        #pragma unroll
        for (int rep = 0; rep < 2; rep++){
            int h = w * 2 + rep;
            const unsigned short* krow = kb + (long)(j0 + l15) * CS + h * 48;
            short8 kf0 = *reinterpret_cast<const short8*>(krow + l4 * 8);
            short8 kf1; for (int b = 0; b < 8; b++) kf1[b] = 0;
            if (l4 < 2) kf1 = *reinterpret_cast<const short8*>(krow + 32 + l4 * 8);
            f32x4 acc = {0.f, 0.f, 0.f, 0.f};
            acc = __builtin_amdgcn_mfma_f32_16x16x32_bf16(qf0[rep], kf0, acc, 0, 0, 0);
            acc = __builtin_amdgcn_mfma_f32_16x16x32_bf16(qf1[rep], kf1, acc, 0, 0, 0);
            #pragma unroll
            for (int r = 0; r < 4; r++)
                Ls2[l4 * 4 + r][l15][h] = acc[r] * scale;
        }
        __syncthreads();

        // ---- combine, write raw logits, online softmax partials ----
        int qw = t >> 4, jl = t & 15;
        #pragma unroll
        for (int p = 0; p < 8; p++){
            int task = p * 32 + qw;
            int ti = task >> 4, th = task & 15;
            float lg = Ls[ti][jl][th] + Ls2[ti][jl][th] + dist_s[ti][jl][th] + prior_s[ti][jl];
            bool mk = (mask_s[ti][jl] != 0);
            lg = mk ? lg : -FLT_MAX;
            attn[(long)th * LC * LC + (long)(I0 + ti) * LC + j0 + jl] = lg;
            float mt = lg;
            for (int mo = 1; mo < 16; mo <<= 1) mt = fmaxf(mt, __shfl_xor(mt, mo));
            float e = mk ? __expf(lg - mt) : 0.f;
            float st = e;
            for (int mo = 1; mo < 16; mo <<= 1) st += __shfl_xor(st, mo);
            float mnew = fmaxf(mreg[p], mt);
            sreg[p] = sreg[p] * __expf(mreg[p] - mnew) + st * __expf(mt - mnew);
            mreg[p] = mnew;
        }
        __syncthreads();
    }
    if ((t & 15) == 0){
        int qw = t >> 4;
        #pragma unroll
        for (int p = 0; p < 8; p++){
            int task = p * 32 + qw;
            int ti = task >> 4, th = task & 15;
            long off = (((long)th * LC + (I0 + ti)) * 8 + chunk) * 2;
            stats[off]     = mreg[p];
            stats[off + 1] = sreg[p];
        }
    }
}

// ---------------- K3: finalize softmax in-place + ctx = attn @ v ----------------
// grid (16 h, 32 ib) x 256 thr. 32 rows per block; wave pairs split the j range.
__global__ __launch_bounds__(256) void k_ctx(
    float* __restrict__ attn,
    const unsigned short* __restrict__ vt,    // [768][1024] bf16
    const float* __restrict__ stats,
    unsigned short* __restrict__ ctx)         // [1024][768] bf16
{
    __shared__ float red[2][16][49];
    int h = blockIdx.x, ib = blockIdx.y;
    int t = threadIdx.x, lane = t & 63, w = t >> 6;
    int l15 = lane & 15, l4 = lane >> 4;
    int wg = w >> 1, jh = w & 1;
    int i = ib * 32 + wg * 16 + l15;

    const float* sp = stats + ((long)h * LC + i) * 16;   // 8 chunks x 2
    float M = -FLT_MAX;
    for (int c = 0; c < 8; c++) M = fmaxf(M, sp[c * 2]);
    float S = 0.f;
    for (int c = 0; c < 8; c++) S += sp[c * 2 + 1] * __expf(sp[c * 2] - M);
    float invS = 1.0f / S;

    f32x4 zero4 = {0.f, 0.f, 0.f, 0.f};
    f32x4 acc[3] = {zero4, zero4, zero4};
    float* arow = attn + (long)h * LC * LC + (long)i * LC;

    for (int jk = jh * 512; jk < jh * 512 + 512; jk += 32){
        float4 a0 = *reinterpret_cast<const float4*>(arow + jk + l4 * 8);
        float4 a1 = *reinterpret_cast<const float4*>(arow + jk + l4 * 8 + 4);
        float p[8] = {a0.x, a0.y, a0.z, a0.w, a1.x, a1.y, a1.z, a1.w};
        short8 pfr;
        #pragma unroll
        for (int b = 0; b < 8; b++){
            float e = __expf(p[b] - M) * invS;   // masked (-FLT_MAX) -> 0
            p[b] = e;
            pfr[b] = (short)f2b(e);
        }
        float4 o0 = {p[0], p[1], p[2], p[3]}, o1 = {p[4], p[5], p[6], p[7]};
        *reinterpret_cast<float4*>(arow + jk + l4 * 8) = o0;
        *reinterpret_cast<float4*>(arow + jk + l4 * 8 + 4) = o1;
        #pragma unroll
        for (int dt = 0; dt < 3; dt++){
            const unsigned short* vrow = vt + (long)(h * 48 + dt * 16 + l15) * LC + jk + l4 * 8;
            short8 bf = *reinterpret_cast<const short8*>(vrow);
            acc[dt] = __builtin_amdgcn_mfma_f32_16x16x32_bf16(pfr, bf, acc[dt], 0, 0, 0);
        }
    }
    if (jh == 1){
        #pragma unroll
        for (int dt = 0; dt < 3; dt++)
            #pragma unroll
            for (int r = 0; r < 4; r++)
                red[wg][l4 * 4 + r][dt * 16 + l15] = acc[dt][r];
    }
    __syncthreads();
    if (jh == 0){
        #pragma unroll
        for (int dt = 0; dt < 3; dt++)
            #pragma unroll
            for (int r = 0; r < 4; r++){
                float v = acc[dt][r] + red[wg][l4 * 4 + r][dt * 16 + l15];
                int rowi = ib * 32 + wg * 16 + l4 * 4 + r;
                ctx[(long)rowi * CS + h * 48 + dt * 16 + l15] = f2b(v);
            }
    }
}

// ---------------- launch ----------------
extern "C" void kernel_launch(void* const* d_in, const int* in_sizes, int n_in,
                              void* d_out, int out_size, void* d_ws, size_t ws_size,
                              hipStream_t stream)
{
    const float* s     = (const float*)d_in[0];
    const float* z     = (const float*)d_in[1];
    const int*   mask  = (const int*)  d_in[2];
    const float* dist  = (const float*)d_in[3];
    const float* prior = (const float*)d_in[4];
    const float* Wq = (const float*)d_in[5];  const float* bq = (const float*)d_in[6];
    const float* Wk = (const float*)d_in[7];  const float* bk = (const float*)d_in[8];
    const float* Wv = (const float*)d_in[9];  const float* bv = (const float*)d_in[10];
    const float* Wz = (const float*)d_in[11];
    const float* Wo = (const float*)d_in[12]; const float* bo = (const float*)d_in[13];
    const float* Wg = (const float*)d_in[14]; const float* bg = (const float*)d_in[15];

    char* ws = (char*)d_ws;
    const size_t SZ_BF = (size_t)LC * CS * 2;       // 1.5 MB
    const size_t SZ_WT = (size_t)CS * CS * 2;       // 1.125 MB
    unsigned short* sb   = (unsigned short*)(ws);
    unsigned short* wcat = (unsigned short*)(ws + SZ_BF);               // 4 x [768][768]
    unsigned short* wot  = (unsigned short*)(ws + SZ_BF + 4 * SZ_WT);
    unsigned short* qb   = (unsigned short*)(ws + SZ_BF + 5 * SZ_WT);
    unsigned short* kb   = (unsigned short*)(ws + 2 * SZ_BF + 5 * SZ_WT);
    unsigned short* vb   = (unsigned short*)(ws + 3 * SZ_BF + 5 * SZ_WT);
    unsigned short* vt   = (unsigned short*)(ws + 4 * SZ_BF + 5 * SZ_WT);
    float*          gate = (float*)        (ws + 5 * SZ_BF + 5 * SZ_WT);
    unsigned short* ctxb = (unsigned short*)(ws + 5 * SZ_BF + 5 * SZ_WT + (size_t)LC * CS * 4);
    float*          stats= (float*)        (ws + 6 * SZ_BF + 5 * SZ_WT + (size_t)LC * CS * 4);

    float* y    = (float*)d_out;
    float* attn = (float*)d_out + (size_t)LC * CS;

    k_convert<<<768, 256, 0, stream>>>(s, sb, LC * CS);
    P5 p;
    p.s[0] = Wq; p.s[1] = Wk; p.s[2] = Wv; p.s[3] = Wg; p.s[4] = Wo;
    p.d[0] = wcat;
    p.d[1] = wcat + (size_t)CS * CS;
    p.d[2] = wcat + 2 * (size_t)CS * CS;
    p.d[3] = wcat + 3 * (size_t)CS * CS;
    p.d[4] = wot;
    k_transpose_w5<<<dim3(24, 24, 5), 256, 0, stream>>>(p);

    k_gemm_qkvg<<<dim3(16, 48), 256, 0, stream>>>(sb, wcat, bq, bk, bv, bg, qb, kb, vb, gate);
    k_transpose_v<<<dim3(32, 24), 256, 0, stream>>>(vb, vt);

    k_logits<<<dim3(64, 8), 512, 0, stream>>>(z, Wz, qb, kb, dist, prior, mask, attn, stats);
    k_ctx<<<dim3(16, 32), 256, 0, stream>>>(attn, vt, stats, ctxb);
    k_gemm_out<<<dim3(16, 12), 256, 0, stream>>>(ctxb, wot, bo, gate, y);
}